// Round 1
// baseline (850.930 us; speedup 1.0000x reference)
//
#include <hip/hip_runtime.h>

#define K_DIM 40960
#define NFEAT 256
#define BATCH 2048

typedef _Float16 f16;
typedef _Float16 f16x8 __attribute__((ext_vector_type(8)));
typedef _Float16 f16x4 __attribute__((ext_vector_type(4)));
typedef _Float16 f16x2 __attribute__((ext_vector_type(2)));
typedef float f32x4 __attribute__((ext_vector_type(4)));
typedef float f32x16 __attribute__((ext_vector_type(16)));

// ---------------- Kernel 0: W fp32 -> fp16 ----------------
__global__ __launch_bounds__(256) void convert_w(
    const float* __restrict__ w1p, const float* __restrict__ w1o,
    f16* __restrict__ w16p, f16* __restrict__ w16o) {
  const long N4 = (long)NFEAT * K_DIM / 4;  // float4s per matrix
  long stride = (long)gridDim.x * blockDim.x;
  for (long i = (long)blockIdx.x * blockDim.x + threadIdx.x; i < 2 * N4; i += stride) {
    const float4* src;
    f16* dst;
    long idx;
    if (i < N4) { src = (const float4*)w1p; dst = w16p; idx = i; }
    else        { src = (const float4*)w1o; dst = w16o; idx = i - N4; }
    float4 v = src[idx];
    f16x4 h;
    h[0] = (f16)v.x; h[1] = (f16)v.y; h[2] = (f16)v.z; h[3] = (f16)v.w;
    *(f16x4*)(dst + idx * 4) = h;
  }
}

// ---------------- Kernel 1: feature-transformer GEMM ----------------
// 512 threads = 8 waves; tile 64 rows x 256 cols; K-chunk 64; split-K S slices.
// mfma_f32_32x32x16_f16, each wave: rows 0-63 (2 row-tiles) x 32 cols.
// A: fp32->f16 staged in XOR-swizzled LDS, double-buffered (2x8KB).
// W: f16 fragments loaded DIRECTLY global->reg (each fragment consumed once
//    per block; LDS round-trip would be pure overhead). W slices are L2/L3
//    resident via g = b % (2S) block ordering (XCD sees 2 slices).
// One raw s_barrier per K-step with manual lgkmcnt(0) drain only -> global
// prefetch loads (A tile t+2, W frags t+2) stay in flight ACROSS barriers.
__global__ __launch_bounds__(512, 4) void ft_gemm(
    const float* __restrict__ Ap, const float* __restrict__ Ao,
    const f16* __restrict__ W16p, const f16* __restrict__ W16o,
    int S, f16* __restrict__ partials) {
  __shared__ f16 Ash[2][64 * 64];   // XOR-swizzled 16B blocks: slot = kb ^ (row&7)

  const int b = blockIdx.x;
  const int G = 2 * S;
  const int g = b % G;
  const int mt = b / G;
  const int persp = g & 1;
  const int s = g >> 1;
  const int mbase = mt * 64;

  const float* A = persp ? Ao : Ap;
  const f16* W16 = persp ? W16o : W16p;

  const int tid = threadIdx.x;
  const int lane = tid & 63;
  const int wv = tid >> 6;     // 0..7: wave owns cols [wv*32, wv*32+32)
  const int l31 = lane & 31;
  const int hi = lane >> 5;    // 0/1: k-half within a fragment

  const int krange = K_DIM / S;
  const int kstart = s * krange;
  const int nit = krange / 64;   // 80 for S=8 (always even for S in {1,2,4,8})

  // ---- A staging geometry: thread covers two float4s of the 64x64 fp32 tile
  const int f0 = tid, f1 = tid + 512;
  const int ar0 = f0 >> 4, ac0 = f0 & 15;
  const int ar1 = f1 >> 4, ac1 = f1 & 15;
  const float* pA0 = A + (size_t)(mbase + ar0) * K_DIM + ac0 * 4;
  const float* pA1 = A + (size_t)(mbase + ar1) * K_DIM + ac1 * 4;
  const int st0 = ar0 * 64 + (((ac0 >> 1) ^ (ar0 & 7)) * 8) + (ac0 & 1) * 4;
  const int st1 = ar1 * 64 + (((ac1 >> 1) ^ (ar1 & 7)) * 8) + (ac1 & 1) * 4;

  // ---- W fragment base: lane reads W16 row (wv*32 + l31), k-half hi
  const f16* Wb = W16 + (size_t)(wv * 32 + l31) * K_DIM + hi * 8;

  // ---- LDS read bases (rows l31 and 32+l31 share (row&7))
  const int r7 = l31 & 7;
  const int rd0 = l31 * 64;
  const int rd1 = (32 + l31) * 64;

  f32x16 acc0, acc1;
#pragma unroll
  for (int i = 0; i < 16; ++i) { acc0[i] = 0.f; acc1[i] = 0.f; }

  float4 pa0, pa1;
  f16x8 pwA[4], pwB[4];

#define LOADA(kk) do { \
    pa0 = *(const float4*)(pA0 + (kk)); \
    pa1 = *(const float4*)(pA1 + (kk)); \
  } while (0)

#define LOADW(dst, kk) do { \
    dst[0] = *(const f16x8*)(Wb + (kk)); \
    dst[1] = *(const f16x8*)(Wb + (kk) + 16); \
    dst[2] = *(const f16x8*)(Wb + (kk) + 32); \
    dst[3] = *(const f16x8*)(Wb + (kk) + 48); \
  } while (0)

#define STAGE(buf) do { \
    f16x4 h0, h1; \
    h0[0] = (f16)pa0.x; h0[1] = (f16)pa0.y; h0[2] = (f16)pa0.z; h0[3] = (f16)pa0.w; \
    h1[0] = (f16)pa1.x; h1[1] = (f16)pa1.y; h1[2] = (f16)pa1.z; h1[3] = (f16)pa1.w; \
    *(f16x4*)&Ash[buf][st0] = h0; \
    *(f16x4*)&Ash[buf][st1] = h1; \
  } while (0)

  // Raw barrier: drain only LDS ops (lgkmcnt); global loads stay in flight.
  // sched_barrier(0) fences both sides (rule 18 / m152 race hygiene).
#define BARRIER() do { \
    asm volatile("s_waitcnt lgkmcnt(0)" ::: "memory"); \
    __builtin_amdgcn_sched_barrier(0); \
    __builtin_amdgcn_s_barrier(); \
    __builtin_amdgcn_sched_barrier(0); \
  } while (0)

#define COMPUTE(buf, pw, knext) do { \
    _Pragma("unroll") \
    for (int ks = 0; ks < 4; ++ks) { \
      const int so = ((ks * 2 + hi) ^ r7) * 8; \
      f16x8 af0 = *(const f16x8*)&Ash[buf][rd0 + so]; \
      f16x8 af1 = *(const f16x8*)&Ash[buf][rd1 + so]; \
      acc0 = __builtin_amdgcn_mfma_f32_32x32x16_f16(af0, pw[ks], acc0, 0, 0, 0); \
      acc1 = __builtin_amdgcn_mfma_f32_32x32x16_f16(af1, pw[ks], acc1, 0, 0, 0); \
      pw[ks] = *(const f16x8*)(Wb + (knext) + ks * 16); \
    } \
  } while (0)

  // ---- prologue: tile0 staged, tile1 + W(iter0, iter1) in flight
  LOADA(kstart);
  LOADW(pwA, kstart);
  STAGE(0);
  const int k1 = kstart + (nit > 1 ? 64 : 0);
  LOADA(k1);
  LOADW(pwB, k1);
  BARRIER();

  for (int t = 0; t < nit; t += 2) {
    const int k0 = kstart + t * 64;
    {  // even step: compute buf0 with pwA; stage tile t+1 -> buf1
      STAGE(1);
      const int kn = (t + 2 < nit) ? (k0 + 128) : kstart;  // clamped garbage ok
      LOADA(kn);
      COMPUTE(0, pwA, kn);
      BARRIER();
    }
    {  // odd step: compute buf1 with pwB; stage tile t+2 -> buf0
      STAGE(0);
      const int kn = (t + 3 < nit) ? (k0 + 192) : kstart;
      LOADA(kn);
      COMPUTE(1, pwB, kn);
      BARRIER();
    }
  }

#undef LOADA
#undef LOADW
#undef STAGE
#undef BARRIER
#undef COMPUTE

  // ---- epilogue: fp16 partials, slice index = g
  // C/D layout (32x32): col = lane&31, row = (reg&3) + 8*(reg>>2) + 4*hi
  f16* pp = partials + (size_t)g * ((size_t)BATCH * NFEAT);
  const int col = wv * 32 + l31;
  const int rbase = mbase + 4 * hi;
#pragma unroll
  for (int q = 0; q < 4; ++q)
#pragma unroll
    for (int i = 0; i < 4; ++i) {
      const int row = rbase + q * 8 + i;
      pp[(size_t)row * NFEAT + col] = (f16)acc0[q * 4 + i];
      pp[(size_t)(row + 32) * NFEAT + col] = (f16)acc1[q * 4 + i];
    }
}

// ---------------- Kernel 2: reduce partials + bias + clip -> combined ------
__global__ __launch_bounds__(256) void reduce_bias(
    const f16* __restrict__ partials, const float* __restrict__ b1p,
    const float* __restrict__ b1o, int S, float* __restrict__ combined) {
  int idx = blockIdx.x * 256 + threadIdx.x;   // 2048 * 256 (2 cols each)
  int r = idx >> 8;
  int c2 = idx & 255;
  int persp = c2 >> 7;
  int n = (c2 & 127) * 2;
  const float* bias = persp ? b1o : b1p;
  float s0 = bias[n], s1 = bias[n + 1];
#pragma unroll 4
  for (int s = 0; s < S; ++s) {
    f16x2 v = *(const f16x2*)(partials + ((size_t)(s * 2 + persp)) * BATCH * NFEAT +
                              (size_t)r * NFEAT + n);
    s0 += (float)v[0]; s1 += (float)v[1];
  }
  s0 = fminf(fmaxf(s0, 0.f), 1.f);
  s1 = fminf(fmaxf(s1, 0.f), 1.f);
  float2 o; o.x = s0; o.y = s1;
  *(float2*)(combined + (size_t)r * 512 + persp * 256 + n) = o;
}

// ---------------- Kernel 3: fused small MLP (layers 2..4) ------------------
__global__ __launch_bounds__(256) void mlp(
    const float* __restrict__ combined, const float* __restrict__ W2,
    const float* __restrict__ b2, const float* __restrict__ W3,
    const float* __restrict__ b3, const float* __restrict__ Wo,
    const float* __restrict__ bo, float* __restrict__ out) {
  __shared__ f16 W2T[512 * 33];   // [k][j], padded: 2-way max bank aliasing
  __shared__ float H1s[8][33];
  __shared__ float H2s[8][33];
  int tid = threadIdx.x;
#pragma unroll
  for (int i = 0; i < 64; ++i) {
    int idx = i * 256 + tid;
    int j = idx >> 9;
    int k = idx & 511;
    W2T[k * 33 + j] = (f16)W2[idx];
  }
  __syncthreads();

  int lr = tid >> 5;   // 0..7 local row
  int j = tid & 31;    // output feature
  int r = blockIdx.x * 8 + lr;

  const float* crow = combined + (size_t)r * 512;
  float acc = b2[j];
#pragma unroll 8
  for (int k = 0; k < 512; ++k) acc += crow[k] * (float)W2T[k * 33 + j];
  H1s[lr][j] = fminf(fmaxf(acc, 0.f), 1.f);
  __syncthreads();

  acc = b3[j];
  const float* w3r = W3 + j * 32;
#pragma unroll
  for (int k = 0; k < 32; ++k) acc += H1s[lr][k] * w3r[k];
  H2s[lr][j] = fminf(fmaxf(acc, 0.f), 1.f);
  __syncthreads();

  if (j == 0) {
    float o = bo[0];
#pragma unroll
    for (int k = 0; k < 32; ++k) o += H2s[lr][k] * Wo[k];
    out[r] = fminf(fmaxf(o, 0.f), 1.f);
  }
}

// ---------------- launch ----------------
extern "C" void kernel_launch(void* const* d_in, const int* in_sizes, int n_in,
                              void* d_out, int out_size, void* d_ws, size_t ws_size,
                              hipStream_t stream) {
  const float* Ap  = (const float*)d_in[0];
  const float* Ao  = (const float*)d_in[1];
  const float* W1p = (const float*)d_in[2];
  const float* b1p = (const float*)d_in[3];
  const float* W1o = (const float*)d_in[4];
  const float* b1o = (const float*)d_in[5];
  const float* W2  = (const float*)d_in[6];
  const float* b2  = (const float*)d_in[7];
  const float* W3  = (const float*)d_in[8];
  const float* b3  = (const float*)d_in[9];
  const float* Wo  = (const float*)d_in[10];
  const float* bo  = (const float*)d_in[11];
  float* out = (float*)d_out;

  const size_t W16B = 2UL * NFEAT * K_DIM * 2;     // 41.9 MB
  const size_t COMB = (size_t)BATCH * 512 * 4;     // 4.2 MB
  auto need = [&](int s) {
    return W16B + (size_t)s * 2 * BATCH * NFEAT * 2 + COMB;  // fp16 partials
  };

  int S = 8;
  while (S > 1 && need(S) > ws_size) S >>= 1;

  char* ws = (char*)d_ws;
  f16* W16p = (f16*)ws;
  f16* W16o = W16p + (size_t)NFEAT * K_DIM;
  f16* partials = (f16*)(ws + W16B);
  float* combined = (float*)(ws + W16B + (size_t)S * 2 * BATCH * NFEAT * 2);

  convert_w<<<1024, 256, 0, stream>>>(W1p, W1o, W16p, W16o);

  int grid = (BATCH / 64) * S * 2;
  ft_gemm<<<grid, 512, 0, stream>>>(Ap, Ao, W16p, W16o, S, partials);

  reduce_bias<<<(BATCH * 256) / 256, 256, 0, stream>>>(partials, b1p, b1o, S, combined);

  mlp<<<BATCH / 8, 256, 0, stream>>>(combined, W2, b2, W3, b3, Wo, bo, out);
}